// Round 9
// baseline (107.501 us; speedup 1.0000x reference)
//
#include <hip/hip_runtime.h>
#include <math.h>

#define BB 16
#define TT 2048
#define CC 32
#define HH 4
#define DD 8

#define KBS2 1040     // per-wave K buffer stride in halves (128*8 + 16 pad)
#define VRS2 136      // V^T row stride in halves (128 + 8 pad)
#define VBS2 (9 * VRS2)
#define ZP 33         // LDS row stride in floats

typedef __fp16 h2  __attribute__((ext_vector_type(2)));
typedef __fp16 h8  __attribute__((ext_vector_type(8)));
typedef float  fx16 __attribute__((ext_vector_type(16)));
typedef int    i4v __attribute__((ext_vector_type(4)));
typedef int    i2v __attribute__((ext_vector_type(2)));

__device__ __forceinline__ h2 pkh(float a, float b) {
#if __has_builtin(__builtin_amdgcn_cvt_pkrtz)
    return __builtin_amdgcn_cvt_pkrtz(a, b);
#else
    h2 r; r.x = (__fp16)a; r.y = (__fp16)b; return r;
#endif
}

__device__ __forceinline__ float fexp2(float x) {
#if __has_builtin(__builtin_amdgcn_exp2f)
    return __builtin_amdgcn_exp2f(x);
#else
    return exp2f(x);
#endif
}

__device__ __forceinline__ int h2bits(h2 v) { return __builtin_bit_cast(int, v); }

__device__ __forceinline__ h8 pk8(float4 a, float4 b) {
    i4v f;
    f.x = h2bits(pkh(a.x, a.y)); f.y = h2bits(pkh(a.z, a.w));
    f.z = h2bits(pkh(b.x, b.y)); f.w = h2bits(pkh(b.z, b.w));
    return __builtin_bit_cast(h8, f);
}

// S (QK^T C-layout) -> exp -> two B-operand P fragments (verified R7-R17).
// Cross-half exchange via v_permlane32_swap (VALU, no DS latency).
__device__ __forceinline__ void makeP(const fx16& S, bool last, int thr, int hi, h8* P) {
    float pe[16];
    #pragma unroll
    for (int r = 0; r < 16; r++) {
        const int ko = (r & 3) + 8 * (r >> 2);
        float sv = S[r];
        if (last) sv = (ko <= thr) ? sv : -INFINITY;
        pe[r] = fexp2(sv);
    }
    int Hh[8];
    #pragma unroll
    for (int i = 0; i < 8; i++) Hh[i] = h2bits(pkh(pe[2*i], pe[2*i+1]));
#if __has_builtin(__builtin_amdgcn_permlane32_swap)
    #pragma unroll
    for (int s = 0; s < 2; s++) {
        const int b0 = 4 * s;
        auto ra = __builtin_amdgcn_permlane32_swap(Hh[b0+0], Hh[b0+2], false, false);
        auto rb = __builtin_amdgcn_permlane32_swap(Hh[b0+1], Hh[b0+3], false, false);
        i2v pa = __builtin_bit_cast(i2v, ra);
        i2v pb = __builtin_bit_cast(i2v, rb);
        i4v f;
        f.x = pa.x; f.y = pb.x; f.z = pa.y; f.w = pb.y;
        P[s] = __builtin_bit_cast(h8, f);
    }
#else
    #pragma unroll
    for (int s = 0; s < 2; s++) {
        const int b0 = 4 * s;
        int own0 = hi ? Hh[b0+2] : Hh[b0+0];
        int own1 = hi ? Hh[b0+3] : Hh[b0+1];
        int snd0 = hi ? Hh[b0+0] : Hh[b0+2];
        int snd1 = hi ? Hh[b0+1] : Hh[b0+3];
        int rcv0 = __shfl_xor(snd0, 32);
        int rcv1 = __shfl_xor(snd1, 32);
        i4v f;
        f.x = hi ? rcv0 : own0;
        f.y = hi ? rcv1 : own1;
        f.z = hi ? own0 : rcv0;
        f.w = hi ? own1 : rcv1;
        P[s] = __builtin_bit_cast(h8, f);
    }
#endif
}

// ---------------- Kernel 1: QKV projection via MFMA (R21, unchanged) ---------
__global__ __launch_bounds__(192, 3) void qkv_kernel(
    const float* __restrict__ x,
    const float* __restrict__ Wq, const float* __restrict__ bq,
    const float* __restrict__ Wk, const float* __restrict__ bk,
    const float* __restrict__ Wv, const float* __restrict__ bv,
    __fp16* __restrict__ Qo, __fp16* __restrict__ Ko, __fp16* __restrict__ Vo)
{
    const int tid  = threadIdx.x;
    const int m    = tid >> 6;              // wave: 0=Q, 1=K, 2=V
    const int lane = tid & 63;
    const int qc   = lane & 31;
    const int hi   = lane >> 5;

    const int row = blockIdx.x * 32 + qc;   // this lane's token (D column)
    const int b   = row >> 11, t = row & 2047;

    const float* W    = (m == 0) ? Wq : (m == 1) ? Wk : Wv;
    const float* bias = (m == 0) ? bq : (m == 1) ? bk : bv;

    const float* xr = x + (size_t)row * CC + 8 * hi;
    h8 B0 = pk8(*(const float4*)(xr),      *(const float4*)(xr + 4));
    h8 B1 = pk8(*(const float4*)(xr + 16), *(const float4*)(xr + 20));

    const float* wr = W + (size_t)qc * CC + 8 * hi;
    h8 A0 = pk8(*(const float4*)(wr),      *(const float4*)(wr + 4));
    h8 A1 = pk8(*(const float4*)(wr + 16), *(const float4*)(wr + 20));

    fx16 zc;
    #pragma unroll
    for (int i = 0; i < 16; i++) zc[i] = 0.0f;
    fx16 D = __builtin_amdgcn_mfma_f32_32x32x16_f16(A0, B0, zc, 0, 0, 0);
    D = __builtin_amdgcn_mfma_f32_32x32x16_f16(A1, B1, D, 0, 0, 0);

    float o[16];
    {
        float4 bb0 = *(const float4*)(bias + 0  + 4 * hi);
        float4 bb1 = *(const float4*)(bias + 8  + 4 * hi);
        float4 bb2 = *(const float4*)(bias + 16 + 4 * hi);
        float4 bb3 = *(const float4*)(bias + 24 + 4 * hi);
        o[0] = D[0] + bb0.x; o[1] = D[1] + bb0.y; o[2]  = D[2]  + bb0.z; o[3]  = D[3]  + bb0.w;
        o[4] = D[4] + bb1.x; o[5] = D[5] + bb1.y; o[6]  = D[6]  + bb1.z; o[7]  = D[7]  + bb1.w;
        o[8] = D[8] + bb2.x; o[9] = D[9] + bb2.y; o[10] = D[10] + bb2.z; o[11] = D[11] + bb2.w;
        o[12] = D[12] + bb3.x; o[13] = D[13] + bb3.y; o[14] = D[14] + bb3.z; o[15] = D[15] + bb3.w;
    }
    if (m == 0) {
        const float qs = 0.3535533905932738f * 1.4426950408889634f;
        #pragma unroll
        for (int r = 0; r < 16; r++) o[r] *= qs;
    }

    if (m == 2) {
        #pragma unroll
        for (int r = 0; r < 16; r++) {
            const int h = r >> 2, d = (r & 3) + 4 * hi;
            Vo[(((size_t)(b * HH + h)) * 9 + d) * TT + t] = (__fp16)o[r];
        }
        const int hA = hi ? 2 : 0, hB = hi ? 3 : 1;
        Vo[(((size_t)(b * HH + hA)) * 9 + 8) * TT + t] = (__fp16)1.0f;
        Vo[(((size_t)(b * HH + hB)) * 9 + 8) * TT + t] = (__fp16)1.0f;
    } else {
        int I0[4], I1[4];
        #pragma unroll
        for (int g = 0; g < 4; g++) {
            I0[g] = h2bits(pkh(o[4*g + 0], o[4*g + 1]));
            I1[g] = h2bits(pkh(o[4*g + 2], o[4*g + 3]));
        }
        i4v fr0, fr1, fr2, fr3;
#if __has_builtin(__builtin_amdgcn_permlane32_swap)
    #define MAKE_FRAG(g, out) { \
        auto ra = __builtin_amdgcn_permlane32_swap(I0[g], I1[g], false, false); \
        auto rb = __builtin_amdgcn_permlane32_swap(I1[g], I0[g], false, false); \
        i2v p1 = __builtin_bit_cast(i2v, ra); \
        i2v p2 = __builtin_bit_cast(i2v, rb); \
        i4v f; \
        f.x = hi ? p2.x : p1.x; \
        f.y = hi ? p1.x : p2.x; \
        f.z = hi ? p2.y : p1.y; \
        f.w = hi ? p1.y : p2.y; \
        out = f; }
#else
    #define MAKE_FRAG(g, out) { \
        int s0 = __shfl_xor(I0[g], 32); \
        int s1 = __shfl_xor(I1[g], 32); \
        i4v f; \
        f.x = hi ? s0 : I0[g]; \
        f.y = hi ? s1 : I1[g]; \
        f.z = hi ? I0[g] : s0; \
        f.w = hi ? I1[g] : s1; \
        out = f; }
#endif
        MAKE_FRAG(0, fr0); MAKE_FRAG(1, fr1); MAKE_FRAG(2, fr2); MAKE_FRAG(3, fr3);
    #undef MAKE_FRAG
        i4v fA = hi ? fr2 : fr0;
        i4v fB = hi ? fr3 : fr1;
        const int gA = hi ? 2 : 0, gB = hi ? 3 : 1;
        __fp16* O = (m == 0) ? Qo : Ko;
        *(i4v*)(O + ((size_t)(b * HH + gA) * TT + t) * DD) = fA;
        *(i4v*)(O + ((size_t)(b * HH + gB) * TT + t) * DD) = fB;
    }
}

// Sweep one contiguous causal key range [ks, ke) for ONE qgroup (base qb,
// fragment qf), accumulating raw numerator+l into O. Wave-private staging,
// 128-key supertiles, depth-1 supertile prefetch, no barriers. All tiles in
// the range satisfy kt <= qb by construction (no causality branch).
__device__ __forceinline__ void sweep(
    const __fp16* __restrict__ kgl, const __fp16* __restrict__ vgl,
    __fp16* kld, __fp16* vld, const __fp16* kb, const __fp16* vb,
    int ks, int ke, int qb, h8 qf, int thr, int hi, int lane,
    fx16& O, const fx16& zc)
{
    if (ks >= ke) return;
    const int nst = (ke - ks + 127) >> 7;
    i4v kpre[2], vpre[3];
    {   // prime prefetch: keys [ks, ks+128)
        #pragma unroll
        for (int r = 0; r < 2; r++) {
            int row = ks + lane + 64 * r; if (row > TT - 1) row = TT - 1;
            kpre[r] = *(const i4v*)(kgl + (size_t)row * DD);
        }
        #pragma unroll
        for (int r = 0; r < 3; r++) {
            int i = lane + 64 * r; if (i > 143) i = 143;
            int col = ks + (i & 15) * 8; if (col > TT - 8) col = TT - 8;
            vpre[r] = *(const i4v*)(vgl + (i >> 4) * TT + col);
        }
    }
    for (int sti = 0; sti < nst; sti++) {
        const int st = ks + sti * 128;
        {   // commit prefetched 128-key tile to wave-private LDS
            i4v* kd = (i4v*)kld;
            #pragma unroll
            for (int r = 0; r < 2; r++) kd[lane + 64 * r] = kpre[r];
            #pragma unroll
            for (int r = 0; r < 3; r++) {
                const int i = lane + 64 * r;
                if (i < 144) *(i4v*)(vld + (i >> 4) * VRS2 + (i & 15) * 8) = vpre[r];
            }
        }
        if (sti + 1 < nst) {   // issue next supertile's global loads
            const int st2 = st + 128;
            #pragma unroll
            for (int r = 0; r < 2; r++) {
                int row = st2 + lane + 64 * r; if (row > TT - 1) row = TT - 1;
                kpre[r] = *(const i4v*)(kgl + (size_t)row * DD);
            }
            #pragma unroll
            for (int r = 0; r < 3; r++) {
                int i = lane + 64 * r; if (i > 143) i = 143;
                int col = st2 + (i & 15) * 8; if (col > TT - 8) col = TT - 8;
                vpre[r] = *(const i4v*)(vgl + (i >> 4) * TT + col);
            }
        }
        const int kend = min(st + 128, ke);
        for (int kt = st; kt < kend; kt += 32) {
            h8 kf = *(const h8*)(kb + (kt - st) * DD);
            fx16 S = __builtin_amdgcn_mfma_f32_32x32x16_f16(kf, qf, zc, 0, 0, 0);
            h8 P[2];
            makeP(S, kt == qb, thr, hi, P);
            #pragma unroll
            for (int s = 0; s < 2; s++) {
                h8 vf = *(const h8*)(vb + (kt - st) + 16 * s);
                O = __builtin_amdgcn_mfma_f32_32x32x16_f16(vf, P[s], O, 0, 0, 0);
            }
        }
    }
}

// ---------------- Kernel 2: attention + projection (R24) ---------------------
// 8 waves (512 thr): wave w = head (w&3), half (w>>2). The 65-visit antithetic
// pair splits by VISIT COUNT with SINGLE-O state:
//   half0: qg2 keys [0,1056)                       = 33 visits (any ip)
//   half1: qg2 keys [1056,(64-ip)*32)  (phase A)   = 31-ip visits
//          then O reset, qg1 keys [0,(ip+1)*32)    = ip+1 visits -> 32 total
// Fixes all prior occupancy-test defects at once: no staging duplication
// (ranges disjoint), no idle waves (balanced for every ip), no dual-O register
// blowup (sequential phases reuse one accumulator, peak ~110 VGPR < 128), full
// 128-key staging depth. 2 blocks/CU (55 KB LDS) = 4 waves/SIMD genuine.
// Disjoint-key partials merge by pure addition (no-max softmax, l-trick).
__global__ __launch_bounds__(512, 4) void attn_kernel(
    const __fp16* __restrict__ Qg, const __fp16* __restrict__ Kg,
    const __fp16* __restrict__ Vg,
    const float* __restrict__ Wp, const float* __restrict__ bp,
    float* __restrict__ out)
{
    __shared__ __align__(16) __fp16 KsS[8 * KBS2];
    __shared__ __align__(16) __fp16 VtS[8 * VBS2];
    __shared__ float zA[64 * ZP];
    __shared__ float zB[64 * ZP];
    __shared__ float lA[64 * 4];
    __shared__ float lB[64 * 4];

    const int tid  = threadIdx.x;
    const int b    = blockIdx.x & 15;
    const int ip   = blockIdx.x >> 4;       // pair index 0..31
    const int w    = tid >> 6;              // wave 0..7
    const int h    = w & 3;                 // head
    const int half = w >> 2;                // 0 = first 33 visits, 1 = last 32
    const int lane = tid & 63;
    const int qc   = lane & 31;
    const int hi   = lane >> 5;

    const int bh  = b * HH + h;
    const int qb1 = 32 * ip;                // light qgroup base
    const int qb2 = 32 * (63 - ip);         // heavy qgroup base

    // zero rows 0-31 of zB/lB (never written by waves); rows 32-63 only when
    // phase A is empty (ip==31). ip is block-uniform -> no write race.
    for (int i = tid; i < 32 * ZP; i += 512) zB[i] = 0.0f;
    if (tid < 128) lB[tid] = 0.0f;
    if (ip == 31) {
        for (int i = tid; i < 32 * ZP; i += 512) zB[32 * ZP + i] = 0.0f;
        if (tid < 128) lB[128 + tid] = 0.0f;
    }

    h8 qf1, qf2;
    {   // B operands: Q^T (pre-scaled); hi half zero (annihilates A garbage)
        h8 qz;
        #pragma unroll
        for (int i = 0; i < 8; i++) qz[i] = (__fp16)0.0f;
        h8 qa = *(const h8*)(Qg + ((size_t)bh * TT + qb1 + qc) * DD);
        h8 qb = *(const h8*)(Qg + ((size_t)bh * TT + qb2 + qc) * DD);
        qf1 = hi ? qz : qa;
        qf2 = hi ? qz : qb;
    }

    fx16 O, zc;
    #pragma unroll
    for (int i = 0; i < 16; i++) { O[i] = 0.0f; zc[i] = 0.0f; }

    const int vrow = (qc < 9) ? qc : 8;     // rows>=9 -> ones row (l trick)
    const int thr  = qc - 4 * hi;

    const __fp16* kgl = Kg + (size_t)bh * TT * DD;
    const __fp16* vgl = Vg + (size_t)bh * 9 * TT;
    __fp16* kld = KsS + w * KBS2;           // wave-private
    __fp16* vld = VtS + w * VBS2;
    const __fp16* kb = kld + qc * DD;
    const __fp16* vb = vld + vrow * VRS2 + 8 * hi;

    if (half == 0) {
        // qg2 main partial: keys [0, 1056)
        sweep(kgl, vgl, kld, vld, kb, vb, 0, 1056, qb2, qf2, thr, hi, lane, O, zc);
        float* z = &zA[(32 + qc) * ZP + h * DD + 4 * hi];
        z[0] = O[0]; z[1] = O[1]; z[2] = O[2]; z[3] = O[3];
        lA[(32 + qc) * 4 + h] = O[4];
    } else {
        // phase A: qg2 tail partial, keys [1056, (64-ip)*32)  (empty at ip=31)
        sweep(kgl, vgl, kld, vld, kb, vb, 1056, (64 - ip) * 32, qb2, qf2,
              thr, hi, lane, O, zc);
        if (ip < 31) {
            float* z = &zB[(32 + qc) * ZP + h * DD + 4 * hi];
            z[0] = O[0]; z[1] = O[1]; z[2] = O[2]; z[3] = O[3];
            lB[(32 + qc) * 4 + h] = O[4];
            #pragma unroll
            for (int i = 0; i < 16; i++) O[i] = 0.0f;
        }
        // phase B: qg1 complete, keys [0, (ip+1)*32)
        sweep(kgl, vgl, kld, vld, kb, vb, 0, (ip + 1) * 32, qb1, qf1,
              thr, hi, lane, O, zc);
        float* z = &zA[qc * ZP + h * DD + 4 * hi];
        z[0] = O[0]; z[1] = O[1]; z[2] = O[2]; z[3] = O[3];
        lA[qc * 4 + h] = O[4];
    }
    __syncthreads();

    {   // merge + in-block projection: 64 rows x 32 cols; 512 thr = (row, 4-col seg)
        const int seg = tid >> 6;           // 0..7 -> cols seg*4..seg*4+3
        const int r = tid & 63;             // rows 0-31 -> qg ip, 32-63 -> qg 63-ip
        float linv[4];
        #pragma unroll
        for (int hh = 0; hh < 4; hh++)
            linv[hh] = 1.0f / (lA[r * 4 + hh] + lB[r * 4 + hh]);
        float zr[CC];
        #pragma unroll
        for (int c = 0; c < CC; c++)
            zr[c] = (zA[r * ZP + c] + zB[r * ZP + c]) * linv[c >> 3];
        float o[4];
        #pragma unroll
        for (int d = 0; d < 4; d++) {
            const int dd = seg * 4 + d;
            float acc = bp[dd];
            #pragma unroll
            for (int c = 0; c < CC; c++) acc += zr[c] * Wp[dd * CC + c];
            o[d] = acc;
        }
        const int qglob = (r < 32) ? (ip * 32 + r) : ((63 - ip) * 32 + (r - 32));
        float* dst = out + ((size_t)b * TT + qglob) * CC + seg * 4;
        *(float4*)dst = make_float4(o[0], o[1], o[2], o[3]);
    }
}

extern "C" void kernel_launch(void* const* d_in, const int* in_sizes, int n_in,
                              void* d_out, int out_size, void* d_ws, size_t ws_size,
                              hipStream_t stream) {
    const float* x  = (const float*)d_in[0];
    const float* Wq = (const float*)d_in[1];
    const float* bq = (const float*)d_in[2];
    const float* Wk = (const float*)d_in[3];
    const float* bk = (const float*)d_in[4];
    const float* Wv = (const float*)d_in[5];
    const float* bv = (const float*)d_in[6];
    const float* Wp = (const float*)d_in[7];
    const float* bp = (const float*)d_in[8];
    float* out = (float*)d_out;

    const size_t NE = (size_t)BB * HH * TT * DD;   // 1M
    __fp16* Qh = (__fp16*)d_ws;                    // 2 MB (pre-scaled)
    __fp16* Kh = Qh + NE;                          // 2 MB
    __fp16* Vt = Kh + NE;                          // 2.25 MB  [bh][9][T]

    qkv_kernel<<<dim3(BB * TT / 32), 192, 0, stream>>>(x, Wq, bq, Wk, bk, Wv, bv, Qh, Kh, Vt);
    attn_kernel<<<dim3(BB * 32), 512, 0, stream>>>(Qh, Kh, Vt, Wp, bp, out);
}

// Round 10
// 104.489 us; speedup vs baseline: 1.0288x; 1.0288x over previous
//
#include <hip/hip_runtime.h>
#include <math.h>

#define BB 16
#define TT 2048
#define CC 32
#define HH 4
#define DD 8

#define KBS 2056      // per-wave K buffer stride in halves (256*8 + 8 pad)
#define VRS 264       // V^T row stride in halves (256 + 8 pad)
#define VBS (9 * VRS) // per-wave V buffer halves
#define ZP 33         // LDS row stride in floats

typedef __fp16 h2  __attribute__((ext_vector_type(2)));
typedef __fp16 h8  __attribute__((ext_vector_type(8)));
typedef float  fx16 __attribute__((ext_vector_type(16)));
typedef int    i4v __attribute__((ext_vector_type(4)));
typedef int    i2v __attribute__((ext_vector_type(2)));

__device__ __forceinline__ h2 pkh(float a, float b) {
#if __has_builtin(__builtin_amdgcn_cvt_pkrtz)
    return __builtin_amdgcn_cvt_pkrtz(a, b);
#else
    h2 r; r.x = (__fp16)a; r.y = (__fp16)b; return r;
#endif
}

__device__ __forceinline__ float fexp2(float x) {
#if __has_builtin(__builtin_amdgcn_exp2f)
    return __builtin_amdgcn_exp2f(x);
#else
    return exp2f(x);
#endif
}

__device__ __forceinline__ int h2bits(h2 v) { return __builtin_bit_cast(int, v); }

__device__ __forceinline__ h8 pk8(float4 a, float4 b) {
    i4v f;
    f.x = h2bits(pkh(a.x, a.y)); f.y = h2bits(pkh(a.z, a.w));
    f.z = h2bits(pkh(b.x, b.y)); f.w = h2bits(pkh(b.z, b.w));
    return __builtin_bit_cast(h8, f);
}

// S (QK^T C-layout) -> exp -> two B-operand P fragments (verified R7-R17).
// Cross-half exchange via v_permlane32_swap (VALU, no DS latency).
__device__ __forceinline__ void makeP(const fx16& S, bool last, int thr, int hi, h8* P) {
    float pe[16];
    #pragma unroll
    for (int r = 0; r < 16; r++) {
        const int ko = (r & 3) + 8 * (r >> 2);
        float sv = S[r];
        if (last) sv = (ko <= thr) ? sv : -INFINITY;
        pe[r] = fexp2(sv);
    }
    int Hh[8];
    #pragma unroll
    for (int i = 0; i < 8; i++) Hh[i] = h2bits(pkh(pe[2*i], pe[2*i+1]));
#if __has_builtin(__builtin_amdgcn_permlane32_swap)
    #pragma unroll
    for (int s = 0; s < 2; s++) {
        const int b0 = 4 * s;
        auto ra = __builtin_amdgcn_permlane32_swap(Hh[b0+0], Hh[b0+2], false, false);
        auto rb = __builtin_amdgcn_permlane32_swap(Hh[b0+1], Hh[b0+3], false, false);
        i2v pa = __builtin_bit_cast(i2v, ra);
        i2v pb = __builtin_bit_cast(i2v, rb);
        i4v f;
        f.x = pa.x; f.y = pb.x; f.z = pa.y; f.w = pb.y;
        P[s] = __builtin_bit_cast(h8, f);
    }
#else
    #pragma unroll
    for (int s = 0; s < 2; s++) {
        const int b0 = 4 * s;
        int own0 = hi ? Hh[b0+2] : Hh[b0+0];
        int own1 = hi ? Hh[b0+3] : Hh[b0+1];
        int snd0 = hi ? Hh[b0+0] : Hh[b0+2];
        int snd1 = hi ? Hh[b0+1] : Hh[b0+3];
        int rcv0 = __shfl_xor(snd0, 32);
        int rcv1 = __shfl_xor(snd1, 32);
        i4v f;
        f.x = hi ? rcv0 : own0;
        f.y = hi ? rcv1 : own1;
        f.z = hi ? own0 : rcv0;
        f.w = hi ? own1 : rcv1;
        P[s] = __builtin_bit_cast(h8, f);
    }
#endif
}

// ---------------- Kernel 1: QKV projection via MFMA (R21, unchanged) ---------
__global__ __launch_bounds__(192, 3) void qkv_kernel(
    const float* __restrict__ x,
    const float* __restrict__ Wq, const float* __restrict__ bq,
    const float* __restrict__ Wk, const float* __restrict__ bk,
    const float* __restrict__ Wv, const float* __restrict__ bv,
    __fp16* __restrict__ Qo, __fp16* __restrict__ Ko, __fp16* __restrict__ Vo)
{
    const int tid  = threadIdx.x;
    const int m    = tid >> 6;              // wave: 0=Q, 1=K, 2=V
    const int lane = tid & 63;
    const int qc   = lane & 31;
    const int hi   = lane >> 5;

    const int row = blockIdx.x * 32 + qc;   // this lane's token (D column)
    const int b   = row >> 11, t = row & 2047;

    const float* W    = (m == 0) ? Wq : (m == 1) ? Wk : Wv;
    const float* bias = (m == 0) ? bq : (m == 1) ? bk : bv;

    const float* xr = x + (size_t)row * CC + 8 * hi;
    h8 B0 = pk8(*(const float4*)(xr),      *(const float4*)(xr + 4));
    h8 B1 = pk8(*(const float4*)(xr + 16), *(const float4*)(xr + 20));

    const float* wr = W + (size_t)qc * CC + 8 * hi;
    h8 A0 = pk8(*(const float4*)(wr),      *(const float4*)(wr + 4));
    h8 A1 = pk8(*(const float4*)(wr + 16), *(const float4*)(wr + 20));

    fx16 zc;
    #pragma unroll
    for (int i = 0; i < 16; i++) zc[i] = 0.0f;
    fx16 D = __builtin_amdgcn_mfma_f32_32x32x16_f16(A0, B0, zc, 0, 0, 0);
    D = __builtin_amdgcn_mfma_f32_32x32x16_f16(A1, B1, D, 0, 0, 0);

    float o[16];
    {
        float4 bb0 = *(const float4*)(bias + 0  + 4 * hi);
        float4 bb1 = *(const float4*)(bias + 8  + 4 * hi);
        float4 bb2 = *(const float4*)(bias + 16 + 4 * hi);
        float4 bb3 = *(const float4*)(bias + 24 + 4 * hi);
        o[0] = D[0] + bb0.x; o[1] = D[1] + bb0.y; o[2]  = D[2]  + bb0.z; o[3]  = D[3]  + bb0.w;
        o[4] = D[4] + bb1.x; o[5] = D[5] + bb1.y; o[6]  = D[6]  + bb1.z; o[7]  = D[7]  + bb1.w;
        o[8] = D[8] + bb2.x; o[9] = D[9] + bb2.y; o[10] = D[10] + bb2.z; o[11] = D[11] + bb2.w;
        o[12] = D[12] + bb3.x; o[13] = D[13] + bb3.y; o[14] = D[14] + bb3.z; o[15] = D[15] + bb3.w;
    }
    if (m == 0) {
        const float qs = 0.3535533905932738f * 1.4426950408889634f;
        #pragma unroll
        for (int r = 0; r < 16; r++) o[r] *= qs;
    }

    if (m == 2) {
        #pragma unroll
        for (int r = 0; r < 16; r++) {
            const int h = r >> 2, d = (r & 3) + 4 * hi;
            Vo[(((size_t)(b * HH + h)) * 9 + d) * TT + t] = (__fp16)o[r];
        }
        const int hA = hi ? 2 : 0, hB = hi ? 3 : 1;
        Vo[(((size_t)(b * HH + hA)) * 9 + 8) * TT + t] = (__fp16)1.0f;
        Vo[(((size_t)(b * HH + hB)) * 9 + 8) * TT + t] = (__fp16)1.0f;
    } else {
        int I0[4], I1[4];
        #pragma unroll
        for (int g = 0; g < 4; g++) {
            I0[g] = h2bits(pkh(o[4*g + 0], o[4*g + 1]));
            I1[g] = h2bits(pkh(o[4*g + 2], o[4*g + 3]));
        }
        i4v fr0, fr1, fr2, fr3;
#if __has_builtin(__builtin_amdgcn_permlane32_swap)
    #define MAKE_FRAG(g, out) { \
        auto ra = __builtin_amdgcn_permlane32_swap(I0[g], I1[g], false, false); \
        auto rb = __builtin_amdgcn_permlane32_swap(I1[g], I0[g], false, false); \
        i2v p1 = __builtin_bit_cast(i2v, ra); \
        i2v p2 = __builtin_bit_cast(i2v, rb); \
        i4v f; \
        f.x = hi ? p2.x : p1.x; \
        f.y = hi ? p1.x : p2.x; \
        f.z = hi ? p2.y : p1.y; \
        f.w = hi ? p1.y : p2.y; \
        out = f; }
#else
    #define MAKE_FRAG(g, out) { \
        int s0 = __shfl_xor(I0[g], 32); \
        int s1 = __shfl_xor(I1[g], 32); \
        i4v f; \
        f.x = hi ? s0 : I0[g]; \
        f.y = hi ? s1 : I1[g]; \
        f.z = hi ? I0[g] : s0; \
        f.w = hi ? I1[g] : s1; \
        out = f; }
#endif
        MAKE_FRAG(0, fr0); MAKE_FRAG(1, fr1); MAKE_FRAG(2, fr2); MAKE_FRAG(3, fr3);
    #undef MAKE_FRAG
        i4v fA = hi ? fr2 : fr0;
        i4v fB = hi ? fr3 : fr1;
        const int gA = hi ? 2 : 0, gB = hi ? 3 : 1;
        __fp16* O = (m == 0) ? Qo : Ko;
        *(i4v*)(O + ((size_t)(b * HH + gA) * TT + t) * DD) = fA;
        *(i4v*)(O + ((size_t)(b * HH + gB) * TT + t) * DD) = fB;
    }
}

// ---------------- Kernel 2: fused attention + projection (R25) ---------------
// R17 structure (4 waves = 4 heads, antithetic pair, wave-private staging,
// register supertile prefetch, no K-loop barriers) with the inner K-loop made
// COMPILE-TIME: full supertiles run a fully-unrolled 8-visit path (ds_reads
// get immediate offsets + batched ahead by the scheduler; per-visit address
// VALU deleted); only the ragged last supertile takes the scalar-tail path.
// s_setprio(1) during compute, 0 during staging (T5, +4-7% attn measured).
__global__ __launch_bounds__(256, 2) void attn_kernel(
    const __fp16* __restrict__ Qg, const __fp16* __restrict__ Kg,
    const __fp16* __restrict__ Vg,
    const float* __restrict__ Wp, const float* __restrict__ bp,
    float* __restrict__ out)
{
    __shared__ __align__(16) __fp16 KsS[4 * KBS];
    __shared__ __align__(16) __fp16 VtS[4 * VBS];
    __shared__ float zbuf[64 * ZP];

    const int tid  = threadIdx.x;
    const int b    = blockIdx.x & 15;
    const int ip   = blockIdx.x >> 4;       // pair index 0..31
    const int h    = tid >> 6;              // wave = head
    const int lane = tid & 63;
    const int qc   = lane & 31;
    const int hi   = lane >> 5;

    const int bh  = b * HH + h;
    const int qb1 = 32 * ip;                // light qgroup base
    const int qb2 = 32 * (63 - ip);         // heavy qgroup base
    const int keys_needed = qb2 + 32;
    const int nst = (keys_needed + 255) >> 8;

    h8 qf1, qf2;
    {   // B operands: Q^T (pre-scaled); hi half zero (annihilates A garbage)
        h8 qz;
        #pragma unroll
        for (int i = 0; i < 8; i++) qz[i] = (__fp16)0.0f;
        h8 qa = *(const h8*)(Qg + ((size_t)bh * TT + qb1 + qc) * DD);
        h8 qb = *(const h8*)(Qg + ((size_t)bh * TT + qb2 + qc) * DD);
        qf1 = hi ? qz : qa;
        qf2 = hi ? qz : qb;
    }

    fx16 O1, O2, zc;
    #pragma unroll
    for (int i = 0; i < 16; i++) { O1[i] = 0.0f; O2[i] = 0.0f; zc[i] = 0.0f; }

    const int vrow = (qc < 9) ? qc : 8;     // rows>=9 -> ones row (l trick)
    const int thr  = qc - 4 * hi;

    const __fp16* kgl = Kg + (size_t)bh * TT * DD;
    const __fp16* vgl = Vg + (size_t)bh * 9 * TT;
    __fp16* kld = KsS + h * KBS;            // wave-private
    __fp16* vld = VtS + h * VBS;
    const __fp16* kb = kld + qc * DD;
    const __fp16* vb = vld + vrow * VRS + 8 * hi;

    i4v kpre[4], vpre[5];
    {   // prefetch super-tile 0
        const i4v* ks = (const i4v*)kgl;
        #pragma unroll
        for (int r = 0; r < 4; r++) kpre[r] = ks[lane + 64 * r];
        #pragma unroll
        for (int r = 0; r < 5; r++) {
            int i = lane + 64 * r; if (i > 287) i = 287;
            vpre[r] = *(const i4v*)(vgl + (i >> 5) * TT + (i & 31) * 8);
        }
    }

    // per-visit compute body; KOFF compile-time on the unrolled path
    #define VISIT(KT, KOFF)                                                     \
    {                                                                           \
        const int kt_ = (KT);                                                   \
        const bool a1 = (kt_ <= qb1);                                           \
        h8 kf = *(const h8*)(kb + (KOFF) * DD);                                 \
        h8 P1[2], P2[2];                                                        \
        if (a1) {                                                               \
            fx16 S = __builtin_amdgcn_mfma_f32_32x32x16_f16(kf, qf1, zc, 0, 0, 0); \
            makeP(S, kt_ == qb1, thr, hi, P1);                                  \
        }                                                                       \
        {                                                                       \
            fx16 S = __builtin_amdgcn_mfma_f32_32x32x16_f16(kf, qf2, zc, 0, 0, 0); \
            makeP(S, kt_ == qb2, thr, hi, P2);                                  \
        }                                                                       \
        _Pragma("unroll")                                                       \
        for (int s = 0; s < 2; s++) {                                           \
            h8 vf = *(const h8*)(vb + (KOFF) + 16 * s);                         \
            if (a1) O1 = __builtin_amdgcn_mfma_f32_32x32x16_f16(vf, P1[s], O1, 0, 0, 0); \
            O2 = __builtin_amdgcn_mfma_f32_32x32x16_f16(vf, P2[s], O2, 0, 0, 0); \
        }                                                                       \
    }

    for (int sti = 0; sti < nst; sti++) {
        const int st = sti * 256;
        {   // commit prefetched tile to wave-private LDS
            i4v* kd = (i4v*)kld;
            #pragma unroll
            for (int r = 0; r < 4; r++) kd[lane + 64 * r] = kpre[r];
            #pragma unroll
            for (int r = 0; r < 5; r++) {
                const int i = lane + 64 * r;
                if (i < 288) *(i4v*)(vld + (i >> 5) * VRS + (i & 31) * 8) = vpre[r];
            }
        }
        if (sti + 1 < nst) {   // issue next tile's global loads (overlap compute)
            const int st2 = st + 256;
            const i4v* ks = (const i4v*)(kgl + (size_t)st2 * DD);
            #pragma unroll
            for (int r = 0; r < 4; r++) kpre[r] = ks[lane + 64 * r];
            #pragma unroll
            for (int r = 0; r < 5; r++) {
                int i = lane + 64 * r; if (i > 287) i = 287;
                vpre[r] = *(const i4v*)(vgl + (i >> 5) * TT + st2 + (i & 31) * 8);
            }
        }

        __builtin_amdgcn_s_setprio(1);
        if (st + 256 <= keys_needed) {
            // full supertile: compile-time 8-visit unroll (immediate ds offsets)
            #pragma unroll
            for (int v = 0; v < 8; v++) {
                VISIT(st + 32 * v, 32 * v)
            }
        } else {
            // ragged last supertile
            for (int kt = st; kt < keys_needed; kt += 32) {
                VISIT(kt, kt - st)
            }
        }
        __builtin_amdgcn_s_setprio(0);
    }
    #undef VISIT

    {   // z -> LDS: O[4] = l (ones-row); regs 0-3 = d0-3 (hi=0) / d4-7 (hi=1)
        const float i1 = 1.0f / O1[4], i2 = 1.0f / O2[4];
        float* z1 = &zbuf[qc * ZP + h * DD + 4 * hi];
        float* z2 = &zbuf[(32 + qc) * ZP + h * DD + 4 * hi];
        z1[0] = O1[0]*i1; z1[1] = O1[1]*i1; z1[2] = O1[2]*i1; z1[3] = O1[3]*i1;
        z2[0] = O2[0]*i2; z2[1] = O2[1]*i2; z2[2] = O2[2]*i2; z2[3] = O2[3]*i2;
    }
    __syncthreads();

    {   // in-block projection: wave = 8-col output segment (uniform Wp -> s_loads)
        const int seg = tid >> 6;
        const int r = tid & 63;             // rows 0-31 -> qg ip, 32-63 -> qg 63-ip
        float zr[CC];
        #pragma unroll
        for (int c = 0; c < CC; c++) zr[c] = zbuf[r * ZP + c];
        float o[DD];
        #pragma unroll
        for (int d = 0; d < DD; d++) {
            const int dd = seg * DD + d;
            float acc = bp[dd];
            #pragma unroll
            for (int c = 0; c < CC; c++) acc += zr[c] * Wp[dd * CC + c];
            o[d] = acc;
        }
        const int qglob = (r < 32) ? (ip * 32 + r) : ((63 - ip) * 32 + (r - 32));
        float* dst = out + ((size_t)b * TT + qglob) * CC + seg * DD;
        ((float4*)dst)[0] = make_float4(o[0], o[1], o[2], o[3]);
        ((float4*)dst)[1] = make_float4(o[4], o[5], o[6], o[7]);
    }
}

extern "C" void kernel_launch(void* const* d_in, const int* in_sizes, int n_in,
                              void* d_out, int out_size, void* d_ws, size_t ws_size,
                              hipStream_t stream) {
    const float* x  = (const float*)d_in[0];
    const float* Wq = (const float*)d_in[1];
    const float* bq = (const float*)d_in[2];
    const float* Wk = (const float*)d_in[3];
    const float* bk = (const float*)d_in[4];
    const float* Wv = (const float*)d_in[5];
    const float* bv = (const float*)d_in[6];
    const float* Wp = (const float*)d_in[7];
    const float* bp = (const float*)d_in[8];
    float* out = (float*)d_out;

    const size_t NE = (size_t)BB * HH * TT * DD;   // 1M
    __fp16* Qh = (__fp16*)d_ws;                    // 2 MB (pre-scaled)
    __fp16* Kh = Qh + NE;                          // 2 MB
    __fp16* Vt = Kh + NE;                          // 2.25 MB  [bh][9][T]

    qkv_kernel<<<dim3(BB * TT / 32), 192, 0, stream>>>(x, Wq, bq, Wk, bk, Wv, bv, Qh, Kh, Vt);
    attn_kernel<<<dim3(BB * 32), 256, 0, stream>>>(Qh, Kh, Vt, Wp, bp, out);
}

// Round 12
// 102.385 us; speedup vs baseline: 1.0500x; 1.0206x over previous
//
#include <hip/hip_runtime.h>
#include <math.h>

#define BB 16
#define TT 2048
#define CC 32
#define HH 4
#define DD 8

#define KBS 2056      // per-wave K buffer stride in halves (256*8 + 8 pad)
#define VRS 264       // V^T row stride in halves (256 + 8 pad)
#define VBS (9 * VRS) // per-wave V buffer halves
#define ZP 33         // LDS row stride in floats

typedef __fp16 h2  __attribute__((ext_vector_type(2)));
typedef __fp16 h8  __attribute__((ext_vector_type(8)));
typedef float  fx16 __attribute__((ext_vector_type(16)));
typedef int    i4v __attribute__((ext_vector_type(4)));
typedef int    i2v __attribute__((ext_vector_type(2)));

__device__ __forceinline__ h2 pkh(float a, float b) {
#if __has_builtin(__builtin_amdgcn_cvt_pkrtz)
    return __builtin_amdgcn_cvt_pkrtz(a, b);
#else
    h2 r; r.x = (__fp16)a; r.y = (__fp16)b; return r;
#endif
}

__device__ __forceinline__ float fexp2(float x) {
#if __has_builtin(__builtin_amdgcn_exp2f)
    return __builtin_amdgcn_exp2f(x);
#else
    return exp2f(x);
#endif
}

__device__ __forceinline__ int h2bits(h2 v) { return __builtin_bit_cast(int, v); }

__device__ __forceinline__ h8 pk8(float4 a, float4 b) {
    i4v f;
    f.x = h2bits(pkh(a.x, a.y)); f.y = h2bits(pkh(a.z, a.w));
    f.z = h2bits(pkh(b.x, b.y)); f.w = h2bits(pkh(b.z, b.w));
    return __builtin_bit_cast(h8, f);
}

// S (QK^T C-layout) -> exp -> two B-operand P fragments (verified R7-R17).
// Cross-half exchange via v_permlane32_swap (VALU, no DS latency).
__device__ __forceinline__ void makeP(const fx16& S, bool last, int thr, int hi, h8* P) {
    float pe[16];
    #pragma unroll
    for (int r = 0; r < 16; r++) {
        const int ko = (r & 3) + 8 * (r >> 2);
        float sv = S[r];
        if (last) sv = (ko <= thr) ? sv : -INFINITY;
        pe[r] = fexp2(sv);
    }
    int Hh[8];
    #pragma unroll
    for (int i = 0; i < 8; i++) Hh[i] = h2bits(pkh(pe[2*i], pe[2*i+1]));
#if __has_builtin(__builtin_amdgcn_permlane32_swap)
    #pragma unroll
    for (int s = 0; s < 2; s++) {
        const int b0 = 4 * s;
        auto ra = __builtin_amdgcn_permlane32_swap(Hh[b0+0], Hh[b0+2], false, false);
        auto rb = __builtin_amdgcn_permlane32_swap(Hh[b0+1], Hh[b0+3], false, false);
        i2v pa = __builtin_bit_cast(i2v, ra);
        i2v pb = __builtin_bit_cast(i2v, rb);
        i4v f;
        f.x = pa.x; f.y = pb.x; f.z = pa.y; f.w = pb.y;
        P[s] = __builtin_bit_cast(h8, f);
    }
#else
    #pragma unroll
    for (int s = 0; s < 2; s++) {
        const int b0 = 4 * s;
        int own0 = hi ? Hh[b0+2] : Hh[b0+0];
        int own1 = hi ? Hh[b0+3] : Hh[b0+1];
        int snd0 = hi ? Hh[b0+0] : Hh[b0+2];
        int snd1 = hi ? Hh[b0+1] : Hh[b0+3];
        int rcv0 = __shfl_xor(snd0, 32);
        int rcv1 = __shfl_xor(snd1, 32);
        i4v f;
        f.x = hi ? rcv0 : own0;
        f.y = hi ? rcv1 : own1;
        f.z = hi ? own0 : rcv0;
        f.w = hi ? own1 : rcv1;
        P[s] = __builtin_bit_cast(h8, f);
    }
#endif
}

// ---------------- Kernel 1: QKV projection via MFMA (R21, unchanged) ---------
__global__ __launch_bounds__(192, 3) void qkv_kernel(
    const float* __restrict__ x,
    const float* __restrict__ Wq, const float* __restrict__ bq,
    const float* __restrict__ Wk, const float* __restrict__ bk,
    const float* __restrict__ Wv, const float* __restrict__ bv,
    __fp16* __restrict__ Qo, __fp16* __restrict__ Ko, __fp16* __restrict__ Vo)
{
    const int tid  = threadIdx.x;
    const int m    = tid >> 6;              // wave: 0=Q, 1=K, 2=V
    const int lane = tid & 63;
    const int qc   = lane & 31;
    const int hi   = lane >> 5;

    const int row = blockIdx.x * 32 + qc;   // this lane's token (D column)
    const int b   = row >> 11, t = row & 2047;

    const float* W    = (m == 0) ? Wq : (m == 1) ? Wk : Wv;
    const float* bias = (m == 0) ? bq : (m == 1) ? bk : bv;

    const float* xr = x + (size_t)row * CC + 8 * hi;
    h8 B0 = pk8(*(const float4*)(xr),      *(const float4*)(xr + 4));
    h8 B1 = pk8(*(const float4*)(xr + 16), *(const float4*)(xr + 20));

    const float* wr = W + (size_t)qc * CC + 8 * hi;
    h8 A0 = pk8(*(const float4*)(wr),      *(const float4*)(wr + 4));
    h8 A1 = pk8(*(const float4*)(wr + 16), *(const float4*)(wr + 20));

    fx16 zc;
    #pragma unroll
    for (int i = 0; i < 16; i++) zc[i] = 0.0f;
    fx16 D = __builtin_amdgcn_mfma_f32_32x32x16_f16(A0, B0, zc, 0, 0, 0);
    D = __builtin_amdgcn_mfma_f32_32x32x16_f16(A1, B1, D, 0, 0, 0);

    float o[16];
    {
        float4 bb0 = *(const float4*)(bias + 0  + 4 * hi);
        float4 bb1 = *(const float4*)(bias + 8  + 4 * hi);
        float4 bb2 = *(const float4*)(bias + 16 + 4 * hi);
        float4 bb3 = *(const float4*)(bias + 24 + 4 * hi);
        o[0] = D[0] + bb0.x; o[1] = D[1] + bb0.y; o[2]  = D[2]  + bb0.z; o[3]  = D[3]  + bb0.w;
        o[4] = D[4] + bb1.x; o[5] = D[5] + bb1.y; o[6]  = D[6]  + bb1.z; o[7]  = D[7]  + bb1.w;
        o[8] = D[8] + bb2.x; o[9] = D[9] + bb2.y; o[10] = D[10] + bb2.z; o[11] = D[11] + bb2.w;
        o[12] = D[12] + bb3.x; o[13] = D[13] + bb3.y; o[14] = D[14] + bb3.z; o[15] = D[15] + bb3.w;
    }
    if (m == 0) {
        const float qs = 0.3535533905932738f * 1.4426950408889634f;
        #pragma unroll
        for (int r = 0; r < 16; r++) o[r] *= qs;
    }

    if (m == 2) {
        #pragma unroll
        for (int r = 0; r < 16; r++) {
            const int h = r >> 2, d = (r & 3) + 4 * hi;
            Vo[(((size_t)(b * HH + h)) * 9 + d) * TT + t] = (__fp16)o[r];
        }
        const int hA = hi ? 2 : 0, hB = hi ? 3 : 1;
        Vo[(((size_t)(b * HH + hA)) * 9 + 8) * TT + t] = (__fp16)1.0f;
        Vo[(((size_t)(b * HH + hB)) * 9 + 8) * TT + t] = (__fp16)1.0f;
    } else {
        int I0[4], I1[4];
        #pragma unroll
        for (int g = 0; g < 4; g++) {
            I0[g] = h2bits(pkh(o[4*g + 0], o[4*g + 1]));
            I1[g] = h2bits(pkh(o[4*g + 2], o[4*g + 3]));
        }
        i4v fr0, fr1, fr2, fr3;
#if __has_builtin(__builtin_amdgcn_permlane32_swap)
    #define MAKE_FRAG(g, out) { \
        auto ra = __builtin_amdgcn_permlane32_swap(I0[g], I1[g], false, false); \
        auto rb = __builtin_amdgcn_permlane32_swap(I1[g], I0[g], false, false); \
        i2v p1 = __builtin_bit_cast(i2v, ra); \
        i2v p2 = __builtin_bit_cast(i2v, rb); \
        i4v f; \
        f.x = hi ? p2.x : p1.x; \
        f.y = hi ? p1.x : p2.x; \
        f.z = hi ? p2.y : p1.y; \
        f.w = hi ? p1.y : p2.y; \
        out = f; }
#else
    #define MAKE_FRAG(g, out) { \
        int s0 = __shfl_xor(I0[g], 32); \
        int s1 = __shfl_xor(I1[g], 32); \
        i4v f; \
        f.x = hi ? s0 : I0[g]; \
        f.y = hi ? s1 : I1[g]; \
        f.z = hi ? I0[g] : s0; \
        f.w = hi ? I1[g] : s1; \
        out = f; }
#endif
        MAKE_FRAG(0, fr0); MAKE_FRAG(1, fr1); MAKE_FRAG(2, fr2); MAKE_FRAG(3, fr3);
    #undef MAKE_FRAG
        i4v fA = hi ? fr2 : fr0;
        i4v fB = hi ? fr3 : fr1;
        const int gA = hi ? 2 : 0, gB = hi ? 3 : 1;
        __fp16* O = (m == 0) ? Qo : Ko;
        *(i4v*)(O + ((size_t)(b * HH + gA) * TT + t) * DD) = fA;
        *(i4v*)(O + ((size_t)(b * HH + gB) * TT + t) * DD) = fB;
    }
}

// ---------------- Kernel 2: fused attention + projection (R26, resubmit) -----
// R25 base (R17 structure + 8-visit unroll + setprio) with PAIRED key-tiles:
// two independent S-MFMAs issued back-to-back, then both makePs (32 indep
// exps keep TRANS fed; A's pack/permlane tail overlaps B's exps), then all
// PV MFMAs. Halves the exposed per-visit softmax latency via intra-wave ILP
// (the lever occupancy x5 could not reach). O-accumulation order per qgroup
// unchanged -> bit-identical result.
__global__ __launch_bounds__(256, 2) void attn_kernel(
    const __fp16* __restrict__ Qg, const __fp16* __restrict__ Kg,
    const __fp16* __restrict__ Vg,
    const float* __restrict__ Wp, const float* __restrict__ bp,
    float* __restrict__ out)
{
    __shared__ __align__(16) __fp16 KsS[4 * KBS];
    __shared__ __align__(16) __fp16 VtS[4 * VBS];
    __shared__ float zbuf[64 * ZP];

    const int tid  = threadIdx.x;
    const int b    = blockIdx.x & 15;
    const int ip   = blockIdx.x >> 4;       // pair index 0..31
    const int h    = tid >> 6;              // wave = head
    const int lane = tid & 63;
    const int qc   = lane & 31;
    const int hi   = lane >> 5;

    const int bh  = b * HH + h;
    const int qb1 = 32 * ip;                // light qgroup base
    const int qb2 = 32 * (63 - ip);         // heavy qgroup base
    const int keys_needed = qb2 + 32;
    const int nst = (keys_needed + 255) >> 8;

    h8 qf1, qf2;
    {   // B operands: Q^T (pre-scaled); hi half zero (annihilates A garbage)
        h8 qz;
        #pragma unroll
        for (int i = 0; i < 8; i++) qz[i] = (__fp16)0.0f;
        h8 qa = *(const h8*)(Qg + ((size_t)bh * TT + qb1 + qc) * DD);
        h8 qb = *(const h8*)(Qg + ((size_t)bh * TT + qb2 + qc) * DD);
        qf1 = hi ? qz : qa;
        qf2 = hi ? qz : qb;
    }

    fx16 O1, O2, zc;
    #pragma unroll
    for (int i = 0; i < 16; i++) { O1[i] = 0.0f; O2[i] = 0.0f; zc[i] = 0.0f; }

    const int vrow = (qc < 9) ? qc : 8;     // rows>=9 -> ones row (l trick)
    const int thr  = qc - 4 * hi;

    const __fp16* kgl = Kg + (size_t)bh * TT * DD;
    const __fp16* vgl = Vg + (size_t)bh * 9 * TT;
    __fp16* kld = KsS + h * KBS;            // wave-private
    __fp16* vld = VtS + h * VBS;
    const __fp16* kb = kld + qc * DD;
    const __fp16* vb = vld + vrow * VRS + 8 * hi;

    i4v kpre[4], vpre[5];
    {   // prefetch super-tile 0
        const i4v* ks = (const i4v*)kgl;
        #pragma unroll
        for (int r = 0; r < 4; r++) kpre[r] = ks[lane + 64 * r];
        #pragma unroll
        for (int r = 0; r < 5; r++) {
            int i = lane + 64 * r; if (i > 287) i = 287;
            vpre[r] = *(const i4v*)(vgl + (i >> 5) * TT + (i & 31) * 8);
        }
    }

    // single-visit body (ragged tail only)
    #define VISIT(KT, KOFF)                                                     \
    {                                                                           \
        const int kt_ = (KT);                                                   \
        const bool a1 = (kt_ <= qb1);                                           \
        h8 kf = *(const h8*)(kb + (KOFF) * DD);                                 \
        h8 P1[2], P2[2];                                                        \
        if (a1) {                                                               \
            fx16 S = __builtin_amdgcn_mfma_f32_32x32x16_f16(kf, qf1, zc, 0, 0, 0); \
            makeP(S, kt_ == qb1, thr, hi, P1);                                  \
        }                                                                       \
        {                                                                       \
            fx16 S = __builtin_amdgcn_mfma_f32_32x32x16_f16(kf, qf2, zc, 0, 0, 0); \
            makeP(S, kt_ == qb2, thr, hi, P2);                                  \
        }                                                                       \
        _Pragma("unroll")                                                       \
        for (int s = 0; s < 2; s++) {                                           \
            h8 vf = *(const h8*)(vb + (KOFF) + 16 * s);                         \
            if (a1) O1 = __builtin_amdgcn_mfma_f32_32x32x16_f16(vf, P1[s], O1, 0, 0, 0); \
            O2 = __builtin_amdgcn_mfma_f32_32x32x16_f16(vf, P2[s], O2, 0, 0, 0); \
        }                                                                       \
    }

    // paired body: two independent chains interleaved (A = KT, B = KT+32)
    #define VISIT2(KT, KOFF)                                                    \
    {                                                                           \
        const int ktA = (KT), ktB = (KT) + 32;                                  \
        h8 kfA  = *(const h8*)(kb + (KOFF) * DD);                               \
        h8 kfB  = *(const h8*)(kb + ((KOFF) + 32) * DD);                        \
        h8 vfA0 = *(const h8*)(vb + (KOFF));                                    \
        h8 vfA1 = *(const h8*)(vb + (KOFF) + 16);                               \
        h8 vfB0 = *(const h8*)(vb + (KOFF) + 32);                               \
        h8 vfB1 = *(const h8*)(vb + (KOFF) + 48);                               \
        /* qg2: batched pair (independent S, 32 indep exps) */                  \
        fx16 SA2 = __builtin_amdgcn_mfma_f32_32x32x16_f16(kfA, qf2, zc, 0, 0, 0); \
        fx16 SB2 = __builtin_amdgcn_mfma_f32_32x32x16_f16(kfB, qf2, zc, 0, 0, 0); \
        h8 P2A[2], P2B[2];                                                      \
        makeP(SA2, ktA == qb2, thr, hi, P2A);                                   \
        makeP(SB2, ktB == qb2, thr, hi, P2B);                                   \
        O2 = __builtin_amdgcn_mfma_f32_32x32x16_f16(vfA0, P2A[0], O2, 0, 0, 0); \
        O2 = __builtin_amdgcn_mfma_f32_32x32x16_f16(vfA1, P2A[1], O2, 0, 0, 0); \
        O2 = __builtin_amdgcn_mfma_f32_32x32x16_f16(vfB0, P2B[0], O2, 0, 0, 0); \
        O2 = __builtin_amdgcn_mfma_f32_32x32x16_f16(vfB1, P2B[1], O2, 0, 0, 0); \
        /* qg1: batched pair where active (a1 wave-uniform) */                  \
        const bool a1A = (ktA <= qb1), a1B = (ktB <= qb1);                      \
        if (a1A) {                                                              \
            fx16 SA1 = __builtin_amdgcn_mfma_f32_32x32x16_f16(kfA, qf1, zc, 0, 0, 0); \
            h8 P1A[2];                                                          \
            if (a1B) {                                                          \
                fx16 SB1 = __builtin_amdgcn_mfma_f32_32x32x16_f16(kfB, qf1, zc, 0, 0, 0); \
                h8 P1B[2];                                                      \
                makeP(SA1, ktA == qb1, thr, hi, P1A);                           \
                makeP(SB1, ktB == qb1, thr, hi, P1B);                           \
                O1 = __builtin_amdgcn_mfma_f32_32x32x16_f16(vfA0, P1A[0], O1, 0, 0, 0); \
                O1 = __builtin_amdgcn_mfma_f32_32x32x16_f16(vfA1, P1A[1], O1, 0, 0, 0); \
                O1 = __builtin_amdgcn_mfma_f32_32x32x16_f16(vfB0, P1B[0], O1, 0, 0, 0); \
                O1 = __builtin_amdgcn_mfma_f32_32x32x16_f16(vfB1, P1B[1], O1, 0, 0, 0); \
            } else {                                                            \
                makeP(SA1, ktA == qb1, thr, hi, P1A);                           \
                O1 = __builtin_amdgcn_mfma_f32_32x32x16_f16(vfA0, P1A[0], O1, 0, 0, 0); \
                O1 = __builtin_amdgcn_mfma_f32_32x32x16_f16(vfA1, P1A[1], O1, 0, 0, 0); \
            }                                                                   \
        }                                                                       \
    }

    for (int sti = 0; sti < nst; sti++) {
        const int st = sti * 256;
        {   // commit prefetched tile to wave-private LDS
            i4v* kd = (i4v*)kld;
            #pragma unroll
            for (int r = 0; r < 4; r++) kd[lane + 64 * r] = kpre[r];
            #pragma unroll
            for (int r = 0; r < 5; r++) {
                const int i = lane + 64 * r;
                if (i < 288) *(i4v*)(vld + (i >> 5) * VRS + (i & 31) * 8) = vpre[r];
            }
        }
        if (sti + 1 < nst) {   // issue next tile's global loads (overlap compute)
            const int st2 = st + 256;
            const i4v* ks = (const i4v*)(kgl + (size_t)st2 * DD);
            #pragma unroll
            for (int r = 0; r < 4; r++) kpre[r] = ks[lane + 64 * r];
            #pragma unroll
            for (int r = 0; r < 5; r++) {
                int i = lane + 64 * r; if (i > 287) i = 287;
                vpre[r] = *(const i4v*)(vgl + (i >> 5) * TT + st2 + (i & 31) * 8);
            }
        }

        __builtin_amdgcn_s_setprio(1);
        if (st + 256 <= keys_needed) {
            // full supertile: 4 compile-time pairs (8 visits)
            #pragma unroll
            for (int v = 0; v < 4; v++) {
                VISIT2(st + 64 * v, 64 * v)
            }
        } else {
            // ragged last supertile: pairs then possible odd single
            int kt = st;
            for (; kt + 64 <= keys_needed; kt += 64) {
                VISIT2(kt, kt - st)
            }
            for (; kt < keys_needed; kt += 32) {
                VISIT(kt, kt - st)
            }
        }
        __builtin_amdgcn_s_setprio(0);
    }
    #undef VISIT2
    #undef VISIT

    {   // z -> LDS: O[4] = l (ones-row); regs 0-3 = d0-3 (hi=0) / d4-7 (hi=1)
        const float i1 = 1.0f / O1[4], i2 = 1.0f / O2[4];
        float* z1 = &zbuf[qc * ZP + h * DD + 4 * hi];
        float* z2 = &zbuf[(32 + qc) * ZP + h * DD + 4 * hi];
        z1[0] = O1[0]*i1; z1[1] = O1[1]*i1; z1[2] = O1[2]*i1; z1[3] = O1[3]*i1;
        z2[0] = O2[0]*i2; z2[1] = O2[1]*i2; z2[2] = O2[2]*i2; z2[3] = O2[3]*i2;
    }
    __syncthreads();

    {   // in-block projection: wave = 8-col output segment (uniform Wp -> s_loads)
        const int seg = tid >> 6;
        const int r = tid & 63;             // rows 0-31 -> qg ip, 32-63 -> qg 63-ip
        float zr[CC];
        #pragma unroll
        for (int c = 0; c < CC; c++) zr[c] = zbuf[r * ZP + c];
        float o[DD];
        #pragma unroll
        for (int d = 0; d < DD; d++) {
            const int dd = seg * DD + d;
            float acc = bp[dd];
            #pragma unroll
            for (int c = 0; c < CC; c++) acc += zr[c] * Wp[dd * CC + c];
            o[d] = acc;
        }
        const int qglob = (r < 32) ? (ip * 32 + r) : ((63 - ip) * 32 + (r - 32));
        float* dst = out + ((size_t)b * TT + qglob) * CC + seg * DD;
        ((float4*)dst)[0] = make_float4(o[0], o[1], o[2], o[3]);
        ((float4*)dst)[1] = make_float4(o[4], o[5], o[6], o[7]);
    }
}

extern "C" void kernel_launch(void* const* d_in, const int* in_sizes, int n_in,
                              void* d_out, int out_size, void* d_ws, size_t ws_size,
                              hipStream_t stream) {
    const float* x  = (const float*)d_in[0];
    const float* Wq = (const float*)d_in[1];
    const float* bq = (const float*)d_in[2];
    const float* Wk = (const float*)d_in[3];
    const float* bk = (const float*)d_in[4];
    const float* Wv = (const float*)d_in[5];
    const float* bv = (const float*)d_in[6];
    const float* Wp = (const float*)d_in[7];
    const float* bp = (const float*)d_in[8];
    float* out = (float*)d_out;

    const size_t NE = (size_t)BB * HH * TT * DD;   // 1M
    __fp16* Qh = (__fp16*)d_ws;                    // 2 MB (pre-scaled)
    __fp16* Kh = Qh + NE;                          // 2 MB
    __fp16* Vt = Kh + NE;                          // 2.25 MB  [bh][9][T]

    qkv_kernel<<<dim3(BB * TT / 32), 192, 0, stream>>>(x, Wq, bq, Wk, bk, Wv, bv, Qh, Kh, Vt);
    attn_kernel<<<dim3(BB * 32), 256, 0, stream>>>(Qh, Kh, Vt, Wp, bp, out);
}